// Round 23
// baseline (49.119 us; speedup 1.0000x reference)
//
#include <hip/hip_runtime.h>
#include <cstdint>

#define N_ATOMS 16384
#define NBLK 64
#define NTHR 256
#define G 24
#define NCELLS 13824
#define NCELLS_PAD 14336
#define CPT 14                    // cells per thread in k2 (1024 thr)
#define BOX_LO -48.0f
#define INV_CELL 0.25f            // cell side 4.0
#define SINIT 3.0e38f

// ws layout (~484 KB):
#define OFF_COUNTS 0              // int[2]: n_ctx, n_gen
#define OFF_ACELL 256             // u16[16384]: cell | 0x8000 if gen
#define OFF_POS 33280             // int[16384]: scatter position (both classes)
#define OFF_START 98816           // int[14337]: ctx cell starts
#define OFF_GENIDX 156416         // int[16384]: gen atoms CELL-SORTED
#define OFF_CTX4 222208           // float4[16384] cell-sorted (x,y,z,|x|^2)

__device__ __forceinline__ int cell1(float x) {
    int c = (int)floorf((x - BOX_LO) * INV_CELL);
    return min(max(c, 0), G - 1);
}

__device__ __forceinline__ void ins3(float v, int vi,
                                     float& s1, float& s2, float& s3,
                                     int& i1, int& i2, int& i3)
{
    const bool b1 = v < s1, b2 = v < s2, b3 = v < s3;
    s3 = b2 ? s2 : (b3 ? v : s3);   i3 = b2 ? i2 : (b3 ? vi : i3);
    s2 = b1 ? s1 : (b2 ? v : s2);   i2 = b1 ? i1 : (b2 ? vi : i2);
    s1 = b1 ? v : s1;               i1 = b1 ? vi : i1;
}

// K1: classify + base_noise + per-atom cell id for ALL atoms (gen tagged 0x8000)
__global__ __launch_bounds__(NTHR)
void k1_classify(const float* __restrict__ X,
                 const int* __restrict__ block_ids,
                 const unsigned int* __restrict__ mask,
                 const float* __restrict__ base_noise,
                 float* __restrict__ out,
                 unsigned short* __restrict__ acell)
{
    __shared__ int sflag;
    const int t = threadIdx.x;

    // mask dtype probe: int32 0/1 values vs packed bool bytes (R2-R22 validated)
    if (t == 0) sflag = 0;
    __syncthreads();
    if (mask[t] > 1u) sflag = 1;    // benign same-value race
    __syncthreads();
    const bool is_u8 = (sflag != 0);
    const unsigned char* m8 = (const unsigned char*)mask;

    const int i = blockIdx.x * NTHR + t;
    const int bid = block_ids[i];
    const bool g = is_u8 ? (m8[bid] != 0) : (mask[bid] != 0u);

    out[3 * i + 0] = base_noise[3 * i + 0];
    out[3 * i + 1] = base_noise[3 * i + 1];
    out[3 * i + 2] = base_noise[3 * i + 2];

    const float x = X[3 * i], y = X[3 * i + 1], z = X[3 * i + 2];
    const unsigned short c =
        (unsigned short)(((cell1(z) * G + cell1(y)) * G + cell1(x)) |
                         (g ? 0x8000 : 0));
    acell[i] = c;
}

// K2: single-block LDS counting sort with PACKED ctx/gen histogram (R22)
__global__ __launch_bounds__(1024)
void k2_sort(const unsigned short* __restrict__ acell,
             int* __restrict__ cell_start,
             int* __restrict__ pos,
             int* __restrict__ counts)
{
    __shared__ int hist[NCELLS_PAD];          // 57,344 B
    __shared__ int wsum[16], wexc[16];
    const int t = threadIdx.x;
    const int wave = t >> 6, lane = t & 63;

    #pragma unroll
    for (int k = 0; k < CPT; ++k) hist[t * CPT + k] = 0;
    __syncthreads();

    #pragma unroll
    for (int it = 0; it < N_ATOMS / 1024; ++it) {
        const unsigned short c = acell[it * 1024 + t];
        const int bin = c & 0x3FFF;
        const int inc = (c & 0x8000) ? 65536 : 1;
        atomicAdd(&hist[bin], inc);
    }
    __syncthreads();

    int loc[CPT]; int sum = 0;
    #pragma unroll
    for (int k = 0; k < CPT; ++k) {
        const int v = hist[t * CPT + k];
        loc[k] = sum; sum += v;
    }
    int v = sum;
    #pragma unroll
    for (int d = 1; d < 64; d <<= 1) { const int u = __shfl_up(v, d); if (lane >= d) v += u; }
    if (lane == 63) wsum[wave] = v;
    __syncthreads();
    if (t < 16) {
        int v2 = wsum[t];
        const int orig = v2;
        #pragma unroll
        for (int d = 1; d < 16; d <<= 1) { const int u = __shfl_up(v2, d); if (t >= d) v2 += u; }
        wexc[t] = v2 - orig;
    }
    __syncthreads();
    const int base = wexc[wave] + (v - sum);
    #pragma unroll
    for (int k = 0; k < CPT; ++k) {
        const int st = base + loc[k];          // packed (ctx_start, gen_start)
        cell_start[t * CPT + k] = st & 0xFFFF;
        hist[t * CPT + k] = st;                // packed cursor
    }
    if (t == 1023) {
        const int tot = base + sum;
        cell_start[NCELLS_PAD] = tot & 0xFFFF;
        counts[0] = tot & 0xFFFF;
        counts[1] = tot >> 16;
    }
    __syncthreads();

    #pragma unroll
    for (int it = 0; it < N_ATOMS / 1024; ++it) {
        const int i = it * 1024 + t;
        const unsigned short c = acell[i];
        const int bin = c & 0x3FFF;
        const int inc = (c & 0x8000) ? 65536 : 1;
        const int old = atomicAdd(&hist[bin], inc);
        pos[i] = (c & 0x8000) ? (old >> 16) : (old & 0xFFFF);
    }
}

// K3: 64-block parallel scatter (no atomics); gen slots cell-sorted (R22)
__global__ __launch_bounds__(NTHR)
void k3_scatter(const float* __restrict__ X,
                const unsigned short* __restrict__ acell,
                const int* __restrict__ pos,
                float4* __restrict__ ctx4s,
                int* __restrict__ genidx)
{
    const int t = threadIdx.x;
    const int i = blockIdx.x * NTHR + t;
    const unsigned short c = acell[i];
    if (c & 0x8000) {
        genidx[pos[i]] = i;
    } else {
        const float x = X[3 * i], y = X[3 * i + 1], z = X[3 * i + 2];
        float xn = x * x; xn += y * y; xn += z * z;
        ctx4s[pos[i]] = make_float4(x, y, z, xn);
    }
}

// merge-network lane permutes (refcheck'd R20-R22)
#define P_X1(v)  __builtin_amdgcn_update_dpp(v, v, 0xB1, 0xF, 0xF, false)
#define P_X2(v)  __builtin_amdgcn_update_dpp(v, v, 0x4E, 0xF, 0xF, false)
#define P_R4(v)  __builtin_amdgcn_update_dpp(v, v, 0x124, 0xF, 0xF, false)
#define P_R8(v)  __builtin_amdgcn_update_dpp(v, v, 0x128, 0xF, 0xF, false)
#define P_S16(v) __builtin_amdgcn_ds_swizzle(v, 0x401F)
#define P_X32(v) __shfl_xor(v, 32)

// K4: one wave per gen atom. Phase A restructured: 384-candidate chunks with
// ALL 6 gathers issued back-to-back before processing (one memory latency per
// 6 rounds instead of per round — the per-round ~350cyc stall was the one
// mechanism shared by all 8 null variants). Rest: R22 verbatim.
__global__ __launch_bounds__(NTHR)
void k4_search(const float* __restrict__ X,
               const float* __restrict__ cnoise,
               const int* __restrict__ counts,
               const int* __restrict__ cell_start,
               const float4* __restrict__ ctx4s,
               const int* __restrict__ genidx,
               float* __restrict__ out)
{
    const int n_gen = counts[1];
    const int wave = threadIdx.x >> 6, lane = threadIdx.x & 63;
    if ((int)blockIdx.x * 4 >= n_gen) return;
    const int slot = (int)blockIdx.x * 4 + wave;
    if (slot >= n_gen) return;

    const int ai = genidx[slot];
    const float qx = X[3 * ai], qy = X[3 * ai + 1], qz = X[3 * ai + 2];
    float xnq = qx * qx; xnq += qy * qy; xnq += qz * qz;
    const int cqx = cell1(qx), cqy = cell1(qy), cqz = cell1(qz);

    float s1 = SINIT, s2 = SINIT, s3 = SINIT;
    int i1 = 0, i2 = 0, i3 = 0;

    // ---- phase A: r<=1 box as 9 row-segments; 6-deep batched gathers ----
    {
        int st = 0, cnt = 0;
        if (lane < 9) {
            const int dy = lane % 3 - 1, dz = lane / 3 - 1;
            const int cy = cqy + dy, cz = cqz + dz;
            if ((unsigned)cy < G && (unsigned)cz < G) {
                const int xlo = max(cqx - 1, 0), xhi = min(cqx + 1, G - 1);
                const int c0 = (cz * G + cy) * G + xlo;
                st = cell_start[c0];
                cnt = cell_start[c0 + (xhi - xlo + 1)] - st;
            }
        }
        int stv[9], base[10];
        base[0] = 0;
        #pragma unroll
        for (int k = 0; k < 9; ++k) {
            stv[k] = __builtin_amdgcn_readlane(st, k);     // VALU, uniform
            base[k + 1] = base[k] + __builtin_amdgcn_readlane(cnt, k);
        }
        const int T = base[9];
        auto calcP = [&](int j) -> int {
            const int jc = min(j, T - 1);
            int p = stv[0] + jc;
            #pragma unroll
            for (int k = 1; k < 9; ++k)
                p = (jc >= base[k]) ? stv[k] + (jc - base[k]) : p;
            return p;
        };
        for (int bj = 0; bj < T; bj += 384) {
            int pidx[6];
            #pragma unroll
            for (int r = 0; r < 6; ++r)
                pidx[r] = calcP(bj + r * 64 + lane);
            float4 cv[6];
            #pragma unroll
            for (int r = 0; r < 6; ++r)
                cv[r] = ctx4s[pidx[r]];          // 6 independent gathers in flight
            #pragma unroll
            for (int r = 0; r < 6; ++r) {
                if (bj + r * 64 + lane < T) {
                    const float dot = qx * cv[r].x + qy * cv[r].y + qz * cv[r].z;
                    const float sq = (xnq + cv[r].w) - 2.0f * dot;
                    ins3(sq, pidx[r], s1, s2, s3, i1, i2, i3);
                }
            }
        }
    }

    // ballot-count convergence: >=3 values below bound <=> merged m3 below
    auto converged = [&](float bnd) -> bool {
        const int c = __popcll(__ballot(s1 + 0.01f < bnd))
                    + __popcll(__ballot(s2 + 0.01f < bnd))
                    + __popcll(__ballot(s3 + 0.01f < bnd));
        return c >= 3;
    };

    bool done = converged(16.0f);            // (4*1)^2

    if (!done) {
        // ---- ring (1,2]: 34 segments, 1 round ----
        {
            const int P = 1, R = 2;
            const int B = 2 * R + 1;
            const int RP = R - P;
            const int PP = 2 * P + 1;
            const int A = 2 * RP * B;
            const int C = PP * 2 * RP;
            const int NS = A + C + 2 * PP * PP;  // 34
            int st = 0, cnt = 0;
            if (lane < NS) {
                const int u = lane;
                int dy, dz, xlo, xhi;
                if (u < A) {
                    const int q = u / B, rdy = u - q * B;
                    dz = (q < RP) ? (-R + q) : (P + 1 + (q - RP));
                    dy = rdy - R;
                    xlo = cqx - R; xhi = cqx + R;
                } else if (u < A + C) {
                    const int v2 = u - A, W = 2 * RP;
                    const int q = v2 / W, w = v2 - q * W;
                    dz = -P + q;
                    dy = (w < RP) ? (-R + w) : (P + 1 + (w - RP));
                    xlo = cqx - R; xhi = cqx + R;
                } else {
                    const int v2 = u - A - C;
                    const int side = v2 & 1, v3 = v2 >> 1;
                    dy = v3 % PP - P; dz = v3 / PP - P;
                    if (side) { xlo = cqx + P + 1; xhi = cqx + R; }
                    else      { xlo = cqx - R;     xhi = cqx - P - 1; }
                }
                const int cy = cqy + dy, cz = cqz + dz;
                if ((unsigned)cy < G && (unsigned)cz < G) {
                    xlo = max(xlo, 0); xhi = min(xhi, G - 1);
                    if (xlo <= xhi) {
                        const int c0 = (cz * G + cy) * G + xlo;
                        st = cell_start[c0];
                        cnt = cell_start[c0 + (xhi - xlo + 1)] - st;
                    }
                }
            }
            int pre = cnt;
            #pragma unroll
            for (int d = 1; d < 64; d <<= 1) {
                const int u = __shfl_up(pre, d);
                if (lane >= d) pre += u;
            }
            const int T = __shfl(pre, 63);
            const int ebase = pre - cnt;
            const int pk = st - ebase;
            const int iters = (T + 63) >> 6;
            for (int it = 0; it < iters; ++it) {
                const int j = it * 64 + lane;
                const int jc = min(j, T - 1);
                int L = 0;
                #pragma unroll
                for (int stp = 32; stp >= 1; stp >>= 1) {
                    const int cand = L + stp;
                    const int bv = __shfl(ebase, cand);
                    if (bv <= jc) L = cand;
                }
                const int p = __shfl(pk, L) + jc;
                const float4 cc = ctx4s[p];
                if (j < T) {
                    const float dot = qx * cc.x + qy * cc.y + qz * cc.z;
                    const float sq = (xnq + cc.w) - 2.0f * dot;
                    ins3(sq, p, s1, s2, s3, i1, i2, i3);
                }
            }
        }
        done = converged(64.0f);             // (4*2)^2

        if (!done) {
            // ---- deep tail: restart brute-force over ALL ctx, x4 unrolled ----
            s1 = SINIT; s2 = SINIT; s3 = SINIT;
            i1 = 0; i2 = 0; i3 = 0;
            const int n_ctx = counts[0];
            for (int base = 0; base < n_ctx; base += 256) {
                const int pa0 = min(base + 0 * 64 + lane, n_ctx - 1);
                const int pa1 = min(base + 1 * 64 + lane, n_ctx - 1);
                const int pa2 = min(base + 2 * 64 + lane, n_ctx - 1);
                const int pa3 = min(base + 3 * 64 + lane, n_ctx - 1);
                const float4 cv0 = ctx4s[pa0], cv1 = ctx4s[pa1];
                const float4 cv2 = ctx4s[pa2], cv3 = ctx4s[pa3];
                #define TAIL_INS(K, CV, PA) \
                    if (base + (K) * 64 + lane < n_ctx) { \
                        const float dot = qx * (CV).x + qy * (CV).y + qz * (CV).z; \
                        const float sq = (xnq + (CV).w) - 2.0f * dot; \
                        ins3(sq, (PA), s1, s2, s3, i1, i2, i3); \
                    }
                TAIL_INS(0, cv0, pa0) TAIL_INS(1, cv1, pa1)
                TAIL_INS(2, cv2, pa2) TAIL_INS(3, cv3, pa3)
                #undef TAIL_INS
            }
        }
    }

    // ---- final wave merge: DPP/swizzle reduction network ----
    #define MERGE_STEP(PERM) { \
        const float a = __int_as_float(PERM(__float_as_int(s1))); const int ja = PERM(i1); \
        const float b = __int_as_float(PERM(__float_as_int(s2))); const int jb = PERM(i2); \
        const float c = __int_as_float(PERM(__float_as_int(s3))); const int jc = PERM(i3); \
        ins3(a, ja, s1, s2, s3, i1, i2, i3); \
        ins3(b, jb, s1, s2, s3, i1, i2, i3); \
        ins3(c, jc, s1, s2, s3, i1, i2, i3); }
    MERGE_STEP(P_X1)
    MERGE_STEP(P_X2)
    MERGE_STEP(P_R4)
    MERGE_STEP(P_R8)
    MERGE_STEP(P_S16)
    MERGE_STEP(P_X32)
    #undef MERGE_STEP

    if (lane == 0) {
        const float d1 = sqrtf(fmaxf(s1, 0.0f) + 1e-12f);
        const float d2 = sqrtf(fmaxf(s2, 0.0f) + 1e-12f);
        const float d3 = sqrtf(fmaxf(s3, 0.0f) + 1e-12f);
        float w1 = 1.0f / (d1 + 1e-8f);
        float w2 = 1.0f / (d2 + 1e-8f);
        float w3 = 1.0f / (d3 + 1e-8f);
        float wsum = w1 + w2;
        wsum += w3;
        w1 /= wsum; w2 /= wsum; w3 /= wsum;
        const float4 c1 = ctx4s[i1];
        const float4 c2 = ctx4s[i2];
        const float4 c3 = ctx4s[i3];
        float cxo = w1 * c1.x + w2 * c2.x; cxo += w3 * c3.x;
        float cyo = w1 * c1.y + w2 * c2.y; cyo += w3 * c3.y;
        float czo = w1 * c1.z + w2 * c2.z; czo += w3 * c3.z;
        out[3 * ai + 0] = cxo + 0.5f * cnoise[3 * ai + 0];
        out[3 * ai + 1] = cyo + 0.5f * cnoise[3 * ai + 1];
        out[3 * ai + 2] = czo + 0.5f * cnoise[3 * ai + 2];
    }
}

extern "C" void kernel_launch(void* const* d_in, const int* in_sizes, int n_in,
                              void* d_out, int out_size, void* d_ws, size_t ws_size,
                              hipStream_t stream) {
    const float* X          = (const float*)d_in[0];
    const float* base_noise = (const float*)d_in[1];
    const float* cnoise     = (const float*)d_in[2];
    const int*   block_ids  = (const int*)d_in[3];
    const unsigned int* gmask = (const unsigned int*)d_in[4];
    float* out = (float*)d_out;

    char* ws = (char*)d_ws;
    int*    counts     = (int*)(ws + OFF_COUNTS);
    unsigned short* acell = (unsigned short*)(ws + OFF_ACELL);
    int*    pos        = (int*)(ws + OFF_POS);
    int*    cell_start = (int*)(ws + OFF_START);
    int*    genidx     = (int*)(ws + OFF_GENIDX);
    float4* ctx4s      = (float4*)(ws + OFF_CTX4);

    k1_classify<<<NBLK, NTHR, 0, stream>>>(X, block_ids, gmask, base_noise,
                                           out, acell);
    k2_sort<<<1, 1024, 0, stream>>>(acell, cell_start, pos, counts);
    k3_scatter<<<NBLK, NTHR, 0, stream>>>(X, acell, pos, ctx4s, genidx);
    k4_search<<<N_ATOMS / 4, NTHR, 0, stream>>>(X, cnoise, counts, cell_start,
                                                ctx4s, genidx, out);
}